// Round 1
// baseline (79.875 us; speedup 1.0000x reference)
//
#include <hip/hip_runtime.h>
#include <math.h>

#define BB 4
#define LL 1024
#define DD 128
#define UU 32
#define WW 64
#define HALF 32

// Kernel A: q[b,l,u] = x . Wt + bh  (bias folded in), kT[b,u,l] = x . Wx
// 256 threads = 4 waves... actually 4 row-groups of 64 lanes; lane<32 -> q, lane>=32 -> k
__global__ __launch_bounds__(256) void qk_kernel(
    const float* __restrict__ x, const float* __restrict__ Wt,
    const float* __restrict__ Wx, const float* __restrict__ bh,
    float* __restrict__ q, float* __restrict__ kT)
{
    __shared__ float xs[4][DD];
    const int tid = threadIdx.x;
    const int w = tid >> 6, lane = tid & 63;
    const int row = blockIdx.x * 4 + w;            // row = b*LL + l
    const float* xr = x + (size_t)row * DD;
    xs[w][lane]      = xr[lane];
    xs[w][lane + 64] = xr[lane + 64];
    __syncthreads();
    const int u = lane & 31;
    const bool isQ = (lane < 32);
    const float* Wm = isQ ? Wt : Wx;
    float acc = 0.f;
    #pragma unroll 8
    for (int d = 0; d < DD; ++d)
        acc = fmaf(xs[w][d], Wm[d * UU + u], acc);
    if (isQ) {
        q[(size_t)row * UU + u] = acc + bh[u];
    } else {
        const int b = row >> 10, l = row & (LL - 1);
        kT[((size_t)(b * UU + u)) * LL + l] = acc;
    }
}

// Kernel B: one 64-lane wave per query row. Lane l owns window slot j = i-32+l.
__global__ __launch_bounds__(256) void attn_kernel(
    const float* __restrict__ x, const float* __restrict__ q,
    const float* __restrict__ kT, const float* __restrict__ Wa,
    float* __restrict__ out)
{
    __shared__ float qs[4][UU];
    __shared__ float as[4][WW];
    __shared__ float was[UU];
    const int tid = threadIdx.x;
    const int w = tid >> 6, lane = tid & 63;
    if (tid < UU) was[tid] = Wa[tid];
    const int row = blockIdx.x * 4 + w;            // row = b*LL + i
    const int b = row >> 10, i = row & (LL - 1);
    if (lane < UU) qs[w][lane] = q[(size_t)row * UU + lane];
    __syncthreads();

    const int j = i - HALF + lane;                 // window position
    const bool valid = (j >= 0) && (j < LL);
    const int jc = min(max(j, 0), LL - 1);

    // e_j = sum_u Wa_u * tanh(q_u + bh_u + k_{j,u})
    float e;
    {
        float acc = 0.f;
        const float* kp = kT + (size_t)b * UU * LL + jc;
        #pragma unroll
        for (int u = 0; u < UU; ++u) {
            float t = qs[w][u] + kp[(size_t)u * LL];
            // tanh(t) = 1 - 2/(exp(2t)+1); v_exp + v_rcp, exact at +/-inf limits
            float ex = __expf(2.f * t);
            float th = fmaf(-2.f, __builtin_amdgcn_rcpf(ex + 1.f), 1.f);
            acc = fmaf(was[u], th, acc);
        }
        e = valid ? acc : -INFINITY;
    }

    // wave-wide max
    float m = e;
    #pragma unroll
    for (int off = 32; off > 0; off >>= 1)
        m = fmaxf(m, __shfl_xor(m, off));
    float p = valid ? __expf(e - m) : 0.f;
    // wave-wide sum
    float s = p;
    #pragma unroll
    for (int off = 32; off > 0; off >>= 1)
        s += __shfl_xor(s, off);
    const float a = p / (s + 1e-7f);
    as[w][lane] = a;
    __syncthreads();

    // v_i = sum_l a_l * x[b, j_l, :]   (lane d covers d and d+64)
    const float* xb = x + (size_t)(b * LL) * DD;
    float v0 = 0.f, v1 = 0.f;
    const int j0 = i - HALF;
    #pragma unroll 8
    for (int l = 0; l < WW; ++l) {
        const float al = as[w][l];
        const int jl = j0 + l;
        const int jlc = min(max(jl, 0), LL - 1);   // a_l==0 when clamped
        const float* xr = xb + (size_t)jlc * DD;
        v0 = fmaf(al, xr[lane], v0);
        v1 = fmaf(al, xr[lane + 64], v1);
    }
    float* o = out + (size_t)row * DD;
    o[lane]      = v0;
    o[lane + 64] = v1;
}

extern "C" void kernel_launch(void* const* d_in, const int* in_sizes, int n_in,
                              void* d_out, int out_size, void* d_ws, size_t ws_size,
                              hipStream_t stream) {
    const float* x  = (const float*)d_in[0];
    const float* Wt = (const float*)d_in[1];
    const float* Wx = (const float*)d_in[2];
    const float* bh = (const float*)d_in[3];
    const float* Wa = (const float*)d_in[4];
    // d_in[5] = ba : uniform shift of e, cancels exactly in softmax -> unused
    float* out = (float*)d_out;

    float* q  = (float*)d_ws;                       // [B,L,U]  512 KB
    float* kT = q + (size_t)BB * LL * UU;           // [B,U,L]  512 KB

    const int rows = BB * LL;                       // 4096
    qk_kernel<<<rows / 4, 256, 0, stream>>>(x, Wt, Wx, bh, q, kT);
    attn_kernel<<<rows / 4, 256, 0, stream>>>(x, q, kT, Wa, out);
}